// Round 5
// baseline (962.599 us; speedup 1.0000x reference)
//
#include <hip/hip_runtime.h>
#include <hip/hip_bf16.h>
#include <cstdint>
#include <cstddef>

typedef __attribute__((ext_vector_type(8))) short short8;
typedef __attribute__((ext_vector_type(4))) float f32x4;

__device__ inline ushort f2bs(float f) {
    __hip_bfloat16 h = __float2bfloat16(f);
    return *(ushort*)&h;
}
__device__ inline float bu2f(ushort u) {
    return __uint_as_float(((unsigned)u) << 16);
}

// ---------------------------------------------------------------------------
// Full-K-in-LDS MFMA GEMM, 2-phase pipelined B staging.
// C[M x NT*128] = act(A[M x KT] @ Wb[NT*128 x KT]^T + bias)   (C bf16)
// A fp32 (AB=0) or bf16 (AB=1).  SIG=1: A' = sigmoid(A*scale+shift) at staging.
// 256 threads = 4 waves (2x2); A panel staged once; B reg-prefetched per step.
// ---------------------------------------------------------------------------
template <int AB, int BM, int KT, int SIG>
__global__ __launch_bounds__(256) void gemm_fullk(
    const void* __restrict__ Avoid, const short* __restrict__ Wb,
    const float* __restrict__ bias, ushort* __restrict__ C,
    const float* __restrict__ scale, const float* __restrict__ shift,
    int M, int NT, int act)
{
    constexpr int KQ = KT / 32;
    __shared__ short As[BM][KT + 8];
    __shared__ short Bs[128][40];

    const int tid = threadIdx.x;
    const int lane = tid & 63;
    const int w = tid >> 6;
    const int wm = w >> 1, wn = w & 1;
    constexpr int MI = BM / 32;
    const int m0 = blockIdx.x * BM;
    const int lr = lane & 15;
    const int lk = (lane >> 4) * 8;
    const int Ntot = NT * 128;

    // ---- stage the full A panel (BM x KT) ----
    {
        constexpr int TPR = KT / 128;       // threads per row
        const int arow = tid / TPR;
        const int ac0 = (tid % TPR) * 128;
        const bool ok = (m0 + arow) < M;
        if (AB == 0) {
            const float* ap = (const float*)Avoid + (size_t)(m0 + arow) * KT + ac0;
#pragma unroll
            for (int j = 0; j < 16; ++j) {
                float4 x = ok ? *(const float4*)(ap + j * 8)
                              : make_float4(0.f, 0.f, 0.f, 0.f);
                float4 y = ok ? *(const float4*)(ap + j * 8 + 4)
                              : make_float4(0.f, 0.f, 0.f, 0.f);
                short8 v;
                v[0] = f2bs(x.x); v[1] = f2bs(x.y); v[2] = f2bs(x.z); v[3] = f2bs(x.w);
                v[4] = f2bs(y.x); v[5] = f2bs(y.y); v[6] = f2bs(y.z); v[7] = f2bs(y.w);
                *(short8*)&As[arow][ac0 + j * 8] = v;
            }
        } else {
            const short* ap = (const short*)Avoid + (size_t)(m0 + arow) * KT + ac0;
#pragma unroll
            for (int j = 0; j < 16; ++j) {
                short8 v = {};
                if (ok) v = *(const short8*)(ap + j * 8);
                if (SIG) {
#pragma unroll
                    for (int e = 0; e < 8; ++e) {
                        int c = ac0 + j * 8 + e;
                        float f = bu2f((ushort)v[e]) * scale[c] + shift[c];
                        v[e] = (short)f2bs(1.f / (1.f + __expf(-f)));
                    }
                }
                *(short8*)&As[arow][ac0 + j * 8] = v;
            }
        }
    }

    const int trow = tid >> 1;
    const int tcg = (tid & 1) * 16;

    // preload B chunk 0
    short8 r0, r1;
    {
        const short* wp = Wb + (size_t)trow * KT + tcg;
        r0 = *(const short8*)wp;
        r1 = *(const short8*)(wp + 8);
    }

    f32x4 acc[MI][4] = {};
    const int total = NT * KQ;

    for (int idx = 0; idx < total; ++idx) {
        *(short8*)&Bs[trow][tcg] = r0;
        *(short8*)&Bs[trow][tcg + 8] = r1;
        __syncthreads();

        // prefetch next B chunk (hides under MFMA phase)
        const int nidx = idx + 1;
        if (nidx < total) {
            const int nt = nidx / KQ, nk = (nidx % KQ) * 32;
            const short* wp = Wb + (size_t)(nt * 128 + trow) * KT + nk + tcg;
            r0 = *(const short8*)wp;
            r1 = *(const short8*)(wp + 8);
        }

        const int k0 = (idx % KQ) * 32;
        short8 afr[MI], bfr[4];
#pragma unroll
        for (int mi = 0; mi < MI; ++mi)
            afr[mi] = *(const short8*)&As[wm * (BM / 2) + mi * 16 + lr][k0 + lk];
#pragma unroll
        for (int nj = 0; nj < 4; ++nj)
            bfr[nj] = *(const short8*)&Bs[wn * 64 + nj * 16 + lr][lk];
#pragma unroll
        for (int mi = 0; mi < MI; ++mi)
#pragma unroll
            for (int nj = 0; nj < 4; ++nj)
                acc[mi][nj] = __builtin_amdgcn_mfma_f32_16x16x32_bf16(
                    afr[mi], bfr[nj], acc[mi][nj], 0, 0, 0);
        __syncthreads();

        if ((idx % KQ) == KQ - 1) {
            const int t = idx / KQ;
#pragma unroll
            for (int mi = 0; mi < MI; ++mi) {
#pragma unroll
                for (int nj = 0; nj < 4; ++nj) {
                    int gn = t * 128 + wn * 64 + nj * 16 + lr;
                    float b = bias[gn];
#pragma unroll
                    for (int r = 0; r < 4; ++r) {
                        int gm = m0 + wm * (BM / 2) + mi * 16 + (lane >> 4) * 4 + r;
                        if (gm < M) {
                            float v = acc[mi][nj][r] + b;
                            if (act == 1) v = fmaxf(v, 0.f);
                            C[(size_t)gm * Ntot + gn] = f2bs(v);
                        }
                    }
                    acc[mi][nj] = (f32x4){0.f, 0.f, 0.f, 0.f};
                }
            }
        }
    }
}

// ---------------------------------------------------------------------------
// 128x128 GEMM for the tiny classifier tail (Nout=40, fp32 out, W fp32)
// ---------------------------------------------------------------------------
__global__ __launch_bounds__(256) void mfma_gemm_small(
    const short* __restrict__ A, const float* __restrict__ W,
    const float* __restrict__ bias, float* __restrict__ Cf,
    int M, int K, int Nout)
{
    __shared__ short As[128][40];
    __shared__ short Bs[128][40];
    const int tid = threadIdx.x;
    const int lane = tid & 63;
    const int w = tid >> 6;
    const int wm = w >> 1, wn = w & 1;
    const int m0 = blockIdx.y * 128, n0 = blockIdx.x * 128;
    const int trow = tid >> 1;
    const int tcg = (tid & 1) * 16;
    const int lr = lane & 15;
    const int lk = (lane >> 4) * 8;

    f32x4 acc[4][4] = {};

    for (int k0 = 0; k0 < K; k0 += 32) {
        {
            bool ok = (m0 + trow) < M;
            const short* ap = A + (size_t)(m0 + trow) * K + k0 + tcg;
            short8 s0 = {}, s1 = {};
            if (ok) { s0 = *(const short8*)(ap); s1 = *(const short8*)(ap + 8); }
            *(short8*)&As[trow][tcg] = s0;
            *(short8*)&As[trow][tcg + 8] = s1;
        }
        {
            short v[16];
            bool ok = (n0 + trow) < Nout;
            const float* wp = W + (size_t)(n0 + trow) * K + k0 + tcg;
#pragma unroll
            for (int q = 0; q < 4; ++q) {
                float4 t4 = ok ? *(const float4*)(wp + q * 4)
                               : make_float4(0.f, 0.f, 0.f, 0.f);
                v[q * 4 + 0] = f2bs(t4.x); v[q * 4 + 1] = f2bs(t4.y);
                v[q * 4 + 2] = f2bs(t4.z); v[q * 4 + 3] = f2bs(t4.w);
            }
            short8 w0, w1;
#pragma unroll
            for (int j = 0; j < 8; ++j) { w0[j] = v[j]; w1[j] = v[j + 8]; }
            *(short8*)&Bs[trow][tcg] = w0;
            *(short8*)&Bs[trow][tcg + 8] = w1;
        }
        __syncthreads();
        short8 afr[4], bfr[4];
#pragma unroll
        for (int mi = 0; mi < 4; ++mi)
            afr[mi] = *(const short8*)&As[wm * 64 + mi * 16 + lr][lk];
#pragma unroll
        for (int nj = 0; nj < 4; ++nj)
            bfr[nj] = *(const short8*)&Bs[wn * 64 + nj * 16 + lr][lk];
#pragma unroll
        for (int mi = 0; mi < 4; ++mi)
#pragma unroll
            for (int nj = 0; nj < 4; ++nj)
                acc[mi][nj] = __builtin_amdgcn_mfma_f32_16x16x32_bf16(
                    afr[mi], bfr[nj], acc[mi][nj], 0, 0, 0);
        __syncthreads();
    }
#pragma unroll
    for (int mi = 0; mi < 4; ++mi)
#pragma unroll
        for (int nj = 0; nj < 4; ++nj) {
            int gn = n0 + wn * 64 + nj * 16 + lr;
            if (gn >= Nout) continue;
            float b = bias[gn];
#pragma unroll
            for (int r = 0; r < 4; ++r) {
                int gm = m0 + wm * 64 + mi * 16 + (lane >> 4) * 4 + r;
                if (gm < M) Cf[(size_t)gm * Nout + gn] = acc[mi][nj][r] + b;
            }
        }
}

// ---------------------------------------------------------------------------
// utility kernels
// ---------------------------------------------------------------------------
__global__ void zero_words(unsigned* __restrict__ p, size_t n)
{
    size_t i = (size_t)blockIdx.x * blockDim.x + threadIdx.x;
    size_t stride = (size_t)gridDim.x * blockDim.x;
    for (; i < n; i += stride) p[i] = 0u;
}

// one-shot conversion of ALL weights fp32->bf16 into Wall + bias concat.
// quad indices (float4 units); weight segments then 256 bias quads.
__global__ void pack_params(
    const float* __restrict__ Wq, const float* __restrict__ Wk,
    const float* __restrict__ Wv, const float* __restrict__ Wskip,
    const float* __restrict__ W1, const float* __restrict__ W2,
    const float* __restrict__ W3, const float* __restrict__ Wc1,
    const float* __restrict__ bq, const float* __restrict__ bk,
    const float* __restrict__ bv, const float* __restrict__ bskip,
    ushort* __restrict__ Wall, float* __restrict__ bcat)
{
    int q = blockIdx.x * 256 + threadIdx.x;
    if (q < 229376) {
        const float* s; int base4;
        if      (q < 16384)  { s = Wq;    base4 = 0; }
        else if (q < 32768)  { s = Wk;    base4 = 16384; }
        else if (q < 49152)  { s = Wv;    base4 = 32768; }
        else if (q < 65536)  { s = Wskip; base4 = 49152; }
        else if (q < 98304)  { s = W1;    base4 = 65536; }
        else if (q < 163840) { s = W2;    base4 = 98304; }
        else if (q < 196608) { s = W3;    base4 = 163840; }
        else                 { s = Wc1;   base4 = 196608; }
        float4 v = ((const float4*)s)[q - base4];
        ushort4 o;
        o.x = f2bs(v.x); o.y = f2bs(v.y); o.z = f2bs(v.z); o.w = f2bs(v.w);
        ((ushort4*)Wall)[q] = o;
    } else if (q < 229632) {
        int j = q - 229376;               // 0..255
        const float* s = (j < 64) ? bq : (j < 128) ? bk : (j < 192) ? bv : bskip;
        ((float4*)bcat)[j] = ((const float4*)s)[j & 63];
    }
}

__global__ __launch_bounds__(256) void bn_stats512_b(
    const ushort* __restrict__ X, float* __restrict__ sums,
    float* __restrict__ sumsq, int M)
{
    int t = threadIdx.x;  // cols 2t, 2t+1
    float s0 = 0.f, q0 = 0.f, s1 = 0.f, q1 = 0.f;
    for (int r = blockIdx.x; r < M; r += gridDim.x) {
        ushort2 v = *(const ushort2*)(X + (size_t)r * 512 + 2 * t);
        float a = bu2f(v.x), b = bu2f(v.y);
        s0 += a; q0 += a * a;
        s1 += b; q1 += b * b;
    }
    atomicAdd(&sums[2 * t], s0);
    atomicAdd(&sumsq[2 * t], q0);
    atomicAdd(&sums[2 * t + 1], s1);
    atomicAdd(&sumsq[2 * t + 1], q1);
}

__global__ void bn_finalize(const float* __restrict__ sums,
                            const float* __restrict__ sumsq,
                            const float* __restrict__ g,
                            const float* __restrict__ be,
                            float* __restrict__ scale, float* __restrict__ shift,
                            int M, int C)
{
    int c = blockIdx.x * blockDim.x + threadIdx.x;
    if (c >= C) return;
    float mean = sums[c] / (float)M;
    float var = sumsq[c] / (float)M - mean * mean;
    float inv = rsqrtf(var + 1e-5f);
    float sc = g[c] * inv;
    scale[c] = sc;
    shift[c] = be[c] - mean * sc;
}

// ---------------------------------------------------------------------------
// CSR build
// ---------------------------------------------------------------------------
__global__ void count_edges(const int* __restrict__ ei, int* __restrict__ counts, int E)
{
    int i = blockIdx.x * 256 + threadIdx.x;
    if (i < E) atomicAdd(&counts[ei[E + i]], 1);
}

__global__ __launch_bounds__(256) void scan_local(
    const int* __restrict__ cnt, int* __restrict__ excl,
    int* __restrict__ bsums, int n)
{
    __shared__ int s[256];
    int t = threadIdx.x;
    int i = blockIdx.x * 256 + t;
    int v = (i < n) ? cnt[i] : 0;
    s[t] = v;
    __syncthreads();
    for (int off = 1; off < 256; off <<= 1) {
        int u = (t >= off) ? s[t - off] : 0;
        __syncthreads();
        s[t] += u;
        __syncthreads();
    }
    if (i < n) excl[i] = s[t] - v;
    if (t == 255) bsums[blockIdx.x] = s[255];
}

__global__ __launch_bounds__(256) void scan_top(int* __restrict__ bsums, int nb)
{
    __shared__ int s[256];
    int t = threadIdx.x;
    int v = (t < nb) ? bsums[t] : 0;
    s[t] = v;
    __syncthreads();
    for (int off = 1; off < 256; off <<= 1) {
        int u = (t >= off) ? s[t - off] : 0;
        __syncthreads();
        s[t] += u;
        __syncthreads();
    }
    if (t < nb) bsums[t] = s[t] - v;
}

__global__ void scan_add(int* __restrict__ excl, const int* __restrict__ bsums,
                         int* __restrict__ cursor, int n)
{
    int i = blockIdx.x * 256 + threadIdx.x;
    if (i < n) {
        int v = excl[i] + bsums[blockIdx.x];
        excl[i] = v;
        cursor[i] = v;
    }
}

__global__ void fill_edges(const int* __restrict__ ei, int* __restrict__ cursor,
                           int* __restrict__ esrc, int E)
{
    int i = blockIdx.x * 256 + threadIdx.x;
    if (i < E) {
        int dst = ei[E + i];
        int pos = atomicAdd(&cursor[dst], 1);
        esrc[pos] = ei[i];
    }
}

// ---------------------------------------------------------------------------
// Fused attention + skip + hm fusion.  One wave per dst node; QKVS layout per
// node: [Q 256 | K 256 | V 256 | S 256] bf16.  hf = alpha*(msg + S) + beta*hm.
// ---------------------------------------------------------------------------
__global__ __launch_bounds__(256) void edge_attn(
    const int* __restrict__ esrc, const int* __restrict__ offs,
    const int* __restrict__ cnts, const ushort* __restrict__ QKVS,
    const ushort* __restrict__ hmb, const float* __restrict__ alpha,
    const float* __restrict__ beta, ushort* __restrict__ hf, int N)
{
    int node = blockIdx.x * 4 + (threadIdx.x >> 6);
    int lane = threadIdx.x & 63;
    if (node >= N) return;
    int start = offs[node];
    int cnt = cnts[node];

    ushort4 qu = *(const ushort4*)(QKVS + (size_t)node * 1024 + lane * 4);
    float qx = bu2f(qu.x), qy = bu2f(qu.y), qz = bu2f(qu.z), qw = bu2f(qu.w);
    const float s = 0.088388347648318447f; // 1/sqrt(128)

    float m = -INFINITY, d = 0.f;
    float a0 = 0.f, a1 = 0.f, a2 = 0.f, a3 = 0.f;

    ushort4 ku_n = {}, vu_n = {};
    if (cnt > 0) {
        int src0 = esrc[start];
        ku_n = *(const ushort4*)(QKVS + (size_t)src0 * 1024 + 256 + lane * 4);
        vu_n = *(const ushort4*)(QKVS + (size_t)src0 * 1024 + 512 + lane * 4);
    }
    for (int i = 0; i < cnt; ++i) {
        ushort4 ku = ku_n, vu = vu_n;
        if (i + 1 < cnt) {
            int srcn = esrc[start + i + 1];
            ku_n = *(const ushort4*)(QKVS + (size_t)srcn * 1024 + 256 + lane * 4);
            vu_n = *(const ushort4*)(QKVS + (size_t)srcn * 1024 + 512 + lane * 4);
        }
        float p = qx * bu2f(ku.x) + qy * bu2f(ku.y)
                + qz * bu2f(ku.z) + qw * bu2f(ku.w);
        p += __shfl_xor(p, 1);
        p += __shfl_xor(p, 2);
        p += __shfl_xor(p, 4);
        p += __shfl_xor(p, 8);
        p += __shfl_xor(p, 16);
        float l = p * s;
        float mn = fmaxf(m, l);
        float sc = __expf(m - mn);
        float pe = __expf(l - mn);
        d = d * sc + pe;
        a0 = a0 * sc + pe * bu2f(vu.x);
        a1 = a1 * sc + pe * bu2f(vu.y);
        a2 = a2 * sc + pe * bu2f(vu.z);
        a3 = a3 * sc + pe * bu2f(vu.w);
        m = mn;
    }
    float invd = (cnt > 0) ? 1.f / fmaxf(d, 1e-16f) : 0.f;
    float o0 = a0 * invd, o1 = a1 * invd, o2 = a2 * invd, o3 = a3 * invd;

    ushort4 su = *(const ushort4*)(QKVS + (size_t)node * 1024 + 768 + lane * 4);
    ushort4 hm = *(const ushort4*)(hmb + (size_t)node * 256 + lane * 4);
    float al = alpha[0], be = beta[0];
    ushort4 o;
    o.x = f2bs(al * (o0 + bu2f(su.x)) + be * bu2f(hm.x));
    o.y = f2bs(al * (o1 + bu2f(su.y)) + be * bu2f(hm.y));
    o.z = f2bs(al * (o2 + bu2f(su.z)) + be * bu2f(hm.z));
    o.w = f2bs(al * (o3 + bu2f(su.w)) + be * bu2f(hm.w));
    *(ushort4*)(hf + (size_t)node * 256 + lane * 4) = o;
}

// ---------------------------------------------------------------------------
// Launch
// ---------------------------------------------------------------------------
extern "C" void kernel_launch(void* const* d_in, const int* in_sizes, int n_in,
                              void* d_out, int out_size, void* d_ws, size_t ws_size,
                              hipStream_t stream)
{
    const float* x_g   = (const float*)d_in[0];
    const int*   ei    = (const int*)d_in[1];
    const float* x_m   = (const float*)d_in[2];
    const float* Wq    = (const float*)d_in[3];
    const float* bq    = (const float*)d_in[4];
    const float* Wk    = (const float*)d_in[5];
    const float* bk    = (const float*)d_in[6];
    const float* Wv    = (const float*)d_in[7];
    const float* bv    = (const float*)d_in[8];
    const float* Wskip = (const float*)d_in[9];
    const float* bskip = (const float*)d_in[10];
    const float* W1    = (const float*)d_in[11];
    const float* b1    = (const float*)d_in[12];
    const float* g1    = (const float*)d_in[13];
    const float* be1   = (const float*)d_in[14];
    const float* W2    = (const float*)d_in[15];
    const float* b2    = (const float*)d_in[16];
    const float* g2    = (const float*)d_in[17];
    const float* be2   = (const float*)d_in[18];
    const float* W3    = (const float*)d_in[19];
    const float* b3    = (const float*)d_in[20];
    const float* alpha = (const float*)d_in[21];
    const float* beta  = (const float*)d_in[22];
    const float* Wc1   = (const float*)d_in[23];
    const float* bc1   = (const float*)d_in[24];
    const float* Wc2   = (const float*)d_in[25];
    const float* bc2   = (const float*)d_in[26];
    float* out = (float*)d_out;

    const int N = in_sizes[0] / 256;
    const int E = in_sizes[1] / 2;

    float* ws = (float*)d_ws;
    // layout (float units)
    ushort* QKVS = (ushort*)ws;                         // N x 1024 bf16
    ushort* bufA = (ushort*)(ws + (size_t)N * 512);     // N x 512 bf16
    ushort* bufB = (ushort*)(ws + (size_t)N * 768);     // N x 512 bf16
    ushort* hmb  = (ushort*)(ws + (size_t)N * 1024);    // N x 256 bf16
    float* wz = ws + (size_t)N * 1152;

    float* sum1 = wz, *sq1 = wz + 512, *sum2 = wz + 1024, *sq2 = wz + 1536;
    int* counts = (int*)(wz + 2048);
    float* wz2 = wz + 2048 + N;
    float* scale1 = wz2, *shift1 = wz2 + 512;
    float* scale2 = wz2 + 1024, *shift2 = wz2 + 1536;
    int* bsums = (int*)(wz2 + 2048);
    int* offs = bsums + 256;
    int* cursor = offs + N;
    int* esrc = cursor + N;
    short* Wall = (short*)(esrc + E);           // 917504 bf16: Q|K|V|S|W1|W2|W3|Wc1
    float* bcat = (float*)(Wall + 917504);      // 1024 f32
    const short* Wcat = Wall;                   // 1024 x 256
    const short* W1b  = Wall + 262144;          // 512 x 256
    const short* W2b  = Wall + 393216;          // 512 x 512
    const short* W3b  = Wall + 655360;          // 256 x 512
    const short* Wc1b = Wall + 786432;          // 512 x 256

    dim3 blk(256);

    // zero: stats (2048 f32) + counts (N i32), contiguous
    hipLaunchKernelGGL(zero_words, dim3(128), blk, 0, stream,
                       (unsigned*)wz, (size_t)(2048 + N));

    // one-shot weight conversion + bias concat
    hipLaunchKernelGGL(pack_params, dim3(898), blk, 0, stream,
                       Wq, Wk, Wv, Wskip, W1, W2, W3, Wc1,
                       bq, bk, bv, bskip, (ushort*)Wall, bcat);

    // CSR build
    const int nb = (N + 255) / 256;
    hipLaunchKernelGGL(count_edges, dim3((E + 255) / 256), blk, 0, stream, ei, counts, E);
    hipLaunchKernelGGL(scan_local, dim3(nb), blk, 0, stream, counts, offs, bsums, N);
    hipLaunchKernelGGL(scan_top, dim3(1), blk, 0, stream, bsums, nb);
    hipLaunchKernelGGL(scan_add, dim3(nb), blk, 0, stream, offs, bsums, cursor, N);
    hipLaunchKernelGGL(fill_edges, dim3((E + 255) / 256), blk, 0, stream, ei, cursor, esrc, E);

    const int g128 = (N + 127) / 128;
    const int g64 = (N + 63) / 64;

    // ---- MLP branch ----
    // h1raw = x_m @ W1^T + b1   (raw, stats from this)
    hipLaunchKernelGGL((gemm_fullk<0, 128, 256, 0>), dim3(g128), blk, 0, stream,
                       x_m, W1b, b1, bufA, nullptr, nullptr, N, 4, 0);
    hipLaunchKernelGGL(bn_stats512_b, dim3(512), blk, 0, stream, bufA, sum1, sq1, N);
    hipLaunchKernelGGL(bn_finalize, dim3(2), blk, 0, stream, sum1, sq1, g1, be1, scale1, shift1, N, 512);
    // h2raw = sig(bn1(h1raw)) @ W2^T + b2  (BN+sigmoid fused into A-staging)
    hipLaunchKernelGGL((gemm_fullk<1, 64, 512, 1>), dim3(g64), blk, 0, stream,
                       bufA, W2b, b2, bufB, scale1, shift1, N, 4, 0);
    hipLaunchKernelGGL(bn_stats512_b, dim3(512), blk, 0, stream, bufB, sum2, sq2, N);
    hipLaunchKernelGGL(bn_finalize, dim3(2), blk, 0, stream, sum2, sq2, g2, be2, scale2, shift2, N, 512);
    // hm = sig(bn2(h2raw)) @ W3^T + b3
    hipLaunchKernelGGL((gemm_fullk<1, 64, 512, 1>), dim3(g64), blk, 0, stream,
                       bufB, W3b, b3, hmb, scale2, shift2, N, 2, 0);

    // ---- GNN branch: fused Q|K|V|S GEMM ----
    hipLaunchKernelGGL((gemm_fullk<0, 128, 256, 0>), dim3(g128), blk, 0, stream,
                       x_g, Wcat, bcat, QKVS, nullptr, nullptr, N, 8, 0);

    // ---- attention + skip + hm fusion -> hf (bufA) ----
    hipLaunchKernelGGL(edge_attn, dim3((N + 3) / 4), blk, 0, stream,
                       esrc, offs, counts, QKVS, hmb, alpha, beta, bufA, N);

    // ---- classifier head ----
    hipLaunchKernelGGL((gemm_fullk<1, 128, 256, 0>), dim3(g128), blk, 0, stream,
                       bufA, Wc1b, bc1, bufB, nullptr, nullptr, N, 4, 1);
    hipLaunchKernelGGL(mfma_gemm_small, dim3(1, (N + 127) / 128), blk, 0, stream,
                       (const short*)bufB, Wc2, bc2, out, N, 512, 40);
}

// Round 6
// 928.974 us; speedup vs baseline: 1.0362x; 1.0362x over previous
//
#include <hip/hip_runtime.h>
#include <hip/hip_bf16.h>
#include <cstdint>
#include <cstddef>

typedef __attribute__((ext_vector_type(8))) short short8;
typedef __attribute__((ext_vector_type(4))) float f32x4;

__device__ inline ushort f2bs(float f) {
    __hip_bfloat16 h = __float2bfloat16(f);
    return *(ushort*)&h;
}
__device__ inline float bu2f(ushort u) {
    return __uint_as_float(((unsigned)u) << 16);
}

// ---------------------------------------------------------------------------
// Full-K-in-LDS MFMA GEMM v2.  BK=64 phases (32 MFMA/wave/phase), XOR-swizzled
// LDS (conflict-free, zero padding: As[BM*KT] + Bs[128*64] = 80 KB exactly ->
// 2 blocks/CU).  Two argument sets so independent GEMMs share one dispatch:
// blockIdx.x < split -> set0, else set1.
// A fp32 (AB=0) or bf16 (AB=1); SIG=1 applies sigmoid(x*scale+shift) at
// A-staging.  C written bf16.  act=1 -> relu epilogue.
// ---------------------------------------------------------------------------
template <int AB, int BM, int KT, int SIG>
__global__ __launch_bounds__(256) void gemm_v2(
    const void* __restrict__ A0, const short* __restrict__ W0,
    const float* __restrict__ bias0, ushort* __restrict__ C0, int NT0,
    const void* __restrict__ A1, const short* __restrict__ W1,
    const float* __restrict__ bias1, ushort* __restrict__ C1, int NT1,
    int split, const float* __restrict__ scale, const float* __restrict__ shift,
    int M, int act)
{
    constexpr int KQ = KT / 64;            // BK=64 phases per col-tile
    constexpr int MI = BM / 32;
    __shared__ short As[BM * KT];
    __shared__ short Bs[128 * 64];

    const int tid = threadIdx.x;
    const int lane = tid & 63;
    const int w = tid >> 6;
    const int wm = w >> 1, wn = w & 1;
    const int lr = lane & 15;
    const int lkc = lane >> 4;             // k-chunk sub-index 0..3

    const int bsel = (blockIdx.x < (unsigned)split) ? 0 : 1;
    const void* Av = bsel ? A1 : A0;
    const short* Wb = bsel ? W1 : W0;
    const float* bias = bsel ? bias1 : bias0;
    ushort* C = bsel ? C1 : C0;
    const int NT = bsel ? NT1 : NT0;
    const int bx = bsel ? ((int)blockIdx.x - split) : (int)blockIdx.x;
    const int m0 = bx * BM;
    const int Ntot = NT * 128;

    // ---- B phase-0 prefetch (issued early; A-staging hides the latency) ----
    const int btr = tid >> 1;              // B row 0..127
    const int bc0 = (tid & 1) * 4;         // first of 4 16B-chunks
    short8 pb[4];
#pragma unroll
    for (int j = 0; j < 4; ++j)
        pb[j] = *(const short8*)(Wb + (size_t)btr * KT + (bc0 + j) * 8);

    // ---- stage full A panel (BM x KT), swizzled chunks ----
    {
        constexpr int TPR = KT / 128;      // threads per row
        const int ar = tid / TPR;
        const int cg0 = (tid % TPR) * 16;  // first chunk of this thread
        const bool ok = (m0 + ar) < M;
        const int sw = ar & 7;
        if (AB == 0) {
            const float* ap = (const float*)Av + (size_t)(m0 + ar) * KT + cg0 * 8;
#pragma unroll
            for (int j = 0; j < 16; ++j) {
                float4 x = ok ? *(const float4*)(ap + j * 8)
                              : make_float4(0.f, 0.f, 0.f, 0.f);
                float4 y = ok ? *(const float4*)(ap + j * 8 + 4)
                              : make_float4(0.f, 0.f, 0.f, 0.f);
                short8 v;
                v[0] = f2bs(x.x); v[1] = f2bs(x.y); v[2] = f2bs(x.z); v[3] = f2bs(x.w);
                v[4] = f2bs(y.x); v[5] = f2bs(y.y); v[6] = f2bs(y.z); v[7] = f2bs(y.w);
                *(short8*)&As[ar * KT + ((cg0 + j) ^ sw) * 8] = v;
            }
        } else {
            const short* ap = (const short*)Av + (size_t)(m0 + ar) * KT + cg0 * 8;
#pragma unroll
            for (int j = 0; j < 16; ++j) {
                short8 v = {};
                if (ok) v = *(const short8*)(ap + j * 8);
                if (SIG) {
#pragma unroll
                    for (int e = 0; e < 8; ++e) {
                        int c = (cg0 + j) * 8 + e;
                        float f = bu2f((ushort)v[e]) * scale[c] + shift[c];
                        v[e] = (short)f2bs(1.f / (1.f + __expf(-f)));
                    }
                }
                *(short8*)&As[ar * KT + ((cg0 + j) ^ sw) * 8] = v;
            }
        }
    }

    f32x4 acc[MI][4] = {};
    const int total = NT * KQ;
    const int bsw = btr & 7;

    for (int idx = 0; idx < total; ++idx) {
        // write prefetched B tile (128 x 64), swizzled
#pragma unroll
        for (int j = 0; j < 4; ++j)
            *(short8*)&Bs[btr * 64 + ((bc0 + j) ^ bsw) * 8] = pb[j];
        __syncthreads();

        // prefetch next phase's B (hides under MFMA phase)
        const int nidx = idx + 1;
        if (nidx < total) {
            const int nt = nidx / KQ, nk = (nidx % KQ) * 64;
            const short* wp = Wb + (size_t)(nt * 128 + btr) * KT + nk + bc0 * 8;
#pragma unroll
            for (int j = 0; j < 4; ++j)
                pb[j] = *(const short8*)(wp + j * 8);
        }

        const int kc = (idx % KQ) * 8;     // chunk base of this 64-wide k-phase
        short8 afr[2][MI], bfr[2][4];
#pragma unroll
        for (int s = 0; s < 2; ++s)
#pragma unroll
            for (int mi = 0; mi < MI; ++mi) {
                int r = wm * (BM / 2) + mi * 16 + lr;
                int cg = kc + s * 4 + lkc;
                afr[s][mi] = *(const short8*)&As[r * KT + (cg ^ (r & 7)) * 8];
            }
#pragma unroll
        for (int s = 0; s < 2; ++s)
#pragma unroll
            for (int nj = 0; nj < 4; ++nj) {
                int r = wn * 64 + nj * 16 + lr;
                int cg = s * 4 + lkc;
                bfr[s][nj] = *(const short8*)&Bs[r * 64 + (cg ^ (r & 7)) * 8];
            }
#pragma unroll
        for (int s = 0; s < 2; ++s)
#pragma unroll
            for (int mi = 0; mi < MI; ++mi)
#pragma unroll
                for (int nj = 0; nj < 4; ++nj)
                    acc[mi][nj] = __builtin_amdgcn_mfma_f32_16x16x32_bf16(
                        afr[s][mi], bfr[s][nj], acc[mi][nj], 0, 0, 0);
        __syncthreads();

        if ((idx % KQ) == KQ - 1) {
            const int t = idx / KQ;
#pragma unroll
            for (int mi = 0; mi < MI; ++mi) {
#pragma unroll
                for (int nj = 0; nj < 4; ++nj) {
                    int gn = t * 128 + wn * 64 + nj * 16 + lr;
                    float b = bias[gn];
#pragma unroll
                    for (int r = 0; r < 4; ++r) {
                        int gm = m0 + wm * (BM / 2) + mi * 16 + (lane >> 4) * 4 + r;
                        if (gm < M) {
                            float v = acc[mi][nj][r] + b;
                            if (act == 1) v = fmaxf(v, 0.f);
                            C[(size_t)gm * Ntot + gn] = f2bs(v);
                        }
                    }
                    acc[mi][nj] = (f32x4){0.f, 0.f, 0.f, 0.f};
                }
            }
        }
    }
}

// ---------------------------------------------------------------------------
// 128x128 GEMM for the tiny classifier tail (Nout=40, fp32 out, W fp32)
// ---------------------------------------------------------------------------
__global__ __launch_bounds__(256) void mfma_gemm_small(
    const short* __restrict__ A, const float* __restrict__ W,
    const float* __restrict__ bias, float* __restrict__ Cf,
    int M, int K, int Nout)
{
    __shared__ short As[128][40];
    __shared__ short Bs[128][40];
    const int tid = threadIdx.x;
    const int lane = tid & 63;
    const int w = tid >> 6;
    const int wm = w >> 1, wn = w & 1;
    const int m0 = blockIdx.y * 128, n0 = blockIdx.x * 128;
    const int trow = tid >> 1;
    const int tcg = (tid & 1) * 16;
    const int lr = lane & 15;
    const int lk = (lane >> 4) * 8;

    f32x4 acc[4][4] = {};

    for (int k0 = 0; k0 < K; k0 += 32) {
        {
            bool ok = (m0 + trow) < M;
            const short* ap = A + (size_t)(m0 + trow) * K + k0 + tcg;
            short8 s0 = {}, s1 = {};
            if (ok) { s0 = *(const short8*)(ap); s1 = *(const short8*)(ap + 8); }
            *(short8*)&As[trow][tcg] = s0;
            *(short8*)&As[trow][tcg + 8] = s1;
        }
        {
            short v[16];
            bool ok = (n0 + trow) < Nout;
            const float* wp = W + (size_t)(n0 + trow) * K + k0 + tcg;
#pragma unroll
            for (int q = 0; q < 4; ++q) {
                float4 t4 = ok ? *(const float4*)(wp + q * 4)
                               : make_float4(0.f, 0.f, 0.f, 0.f);
                v[q * 4 + 0] = f2bs(t4.x); v[q * 4 + 1] = f2bs(t4.y);
                v[q * 4 + 2] = f2bs(t4.z); v[q * 4 + 3] = f2bs(t4.w);
            }
            short8 w0, w1;
#pragma unroll
            for (int j = 0; j < 8; ++j) { w0[j] = v[j]; w1[j] = v[j + 8]; }
            *(short8*)&Bs[trow][tcg] = w0;
            *(short8*)&Bs[trow][tcg + 8] = w1;
        }
        __syncthreads();
        short8 afr[4], bfr[4];
#pragma unroll
        for (int mi = 0; mi < 4; ++mi)
            afr[mi] = *(const short8*)&As[wm * 64 + mi * 16 + lr][lk];
#pragma unroll
        for (int nj = 0; nj < 4; ++nj)
            bfr[nj] = *(const short8*)&Bs[wn * 64 + nj * 16 + lr][lk];
#pragma unroll
        for (int mi = 0; mi < 4; ++mi)
#pragma unroll
            for (int nj = 0; nj < 4; ++nj)
                acc[mi][nj] = __builtin_amdgcn_mfma_f32_16x16x32_bf16(
                    afr[mi], bfr[nj], acc[mi][nj], 0, 0, 0);
        __syncthreads();
    }
#pragma unroll
    for (int mi = 0; mi < 4; ++mi)
#pragma unroll
        for (int nj = 0; nj < 4; ++nj) {
            int gn = n0 + wn * 64 + nj * 16 + lr;
            if (gn >= Nout) continue;
            float b = bias[gn];
#pragma unroll
            for (int r = 0; r < 4; ++r) {
                int gm = m0 + wm * 64 + mi * 16 + (lane >> 4) * 4 + r;
                if (gm < M) Cf[(size_t)gm * Nout + gn] = acc[mi][nj][r] + b;
            }
        }
}

// ---------------------------------------------------------------------------
// utility kernels
// ---------------------------------------------------------------------------
__global__ void zero_words(unsigned* __restrict__ p, size_t n)
{
    size_t i = (size_t)blockIdx.x * blockDim.x + threadIdx.x;
    size_t stride = (size_t)gridDim.x * blockDim.x;
    for (; i < n; i += stride) p[i] = 0u;
}

__global__ void pack_params(
    const float* __restrict__ Wq, const float* __restrict__ Wk,
    const float* __restrict__ Wv, const float* __restrict__ Wskip,
    const float* __restrict__ W1, const float* __restrict__ W2,
    const float* __restrict__ W3, const float* __restrict__ Wc1,
    const float* __restrict__ bq, const float* __restrict__ bk,
    const float* __restrict__ bv, const float* __restrict__ bskip,
    ushort* __restrict__ Wall, float* __restrict__ bcat)
{
    int q = blockIdx.x * 256 + threadIdx.x;
    if (q < 229376) {
        const float* s; int base4;
        if      (q < 16384)  { s = Wq;    base4 = 0; }
        else if (q < 32768)  { s = Wk;    base4 = 16384; }
        else if (q < 49152)  { s = Wv;    base4 = 32768; }
        else if (q < 65536)  { s = Wskip; base4 = 49152; }
        else if (q < 98304)  { s = W1;    base4 = 65536; }
        else if (q < 163840) { s = W2;    base4 = 98304; }
        else if (q < 196608) { s = W3;    base4 = 163840; }
        else                 { s = Wc1;   base4 = 196608; }
        float4 v = ((const float4*)s)[q - base4];
        ushort4 o;
        o.x = f2bs(v.x); o.y = f2bs(v.y); o.z = f2bs(v.z); o.w = f2bs(v.w);
        ((ushort4*)Wall)[q] = o;
    } else if (q < 229632) {
        int j = q - 229376;               // 0..255
        const float* s = (j < 64) ? bq : (j < 128) ? bk : (j < 192) ? bv : bskip;
        ((float4*)bcat)[j] = ((const float4*)s)[j & 63];
    }
}

__global__ __launch_bounds__(256) void bn_stats512_b(
    const ushort* __restrict__ X, float* __restrict__ sums,
    float* __restrict__ sumsq, int M)
{
    int t = threadIdx.x;  // cols 2t, 2t+1
    float s0 = 0.f, q0 = 0.f, s1 = 0.f, q1 = 0.f;
    for (int r = blockIdx.x; r < M; r += gridDim.x) {
        ushort2 v = *(const ushort2*)(X + (size_t)r * 512 + 2 * t);
        float a = bu2f(v.x), b = bu2f(v.y);
        s0 += a; q0 += a * a;
        s1 += b; q1 += b * b;
    }
    atomicAdd(&sums[2 * t], s0);
    atomicAdd(&sumsq[2 * t], q0);
    atomicAdd(&sums[2 * t + 1], s1);
    atomicAdd(&sumsq[2 * t + 1], q1);
}

__global__ void bn_finalize(const float* __restrict__ sums,
                            const float* __restrict__ sumsq,
                            const float* __restrict__ g,
                            const float* __restrict__ be,
                            float* __restrict__ scale, float* __restrict__ shift,
                            int M, int C)
{
    int c = blockIdx.x * blockDim.x + threadIdx.x;
    if (c >= C) return;
    float mean = sums[c] / (float)M;
    float var = sumsq[c] / (float)M - mean * mean;
    float inv = rsqrtf(var + 1e-5f);
    float sc = g[c] * inv;
    scale[c] = sc;
    shift[c] = be[c] - mean * sc;
}

// ---------------------------------------------------------------------------
// CSR build
// ---------------------------------------------------------------------------
__global__ void count_edges(const int* __restrict__ ei, int* __restrict__ counts, int E)
{
    int i = blockIdx.x * 256 + threadIdx.x;
    if (i < E) atomicAdd(&counts[ei[E + i]], 1);
}

__global__ __launch_bounds__(256) void scan_local(
    const int* __restrict__ cnt, int* __restrict__ excl,
    int* __restrict__ bsums, int n)
{
    __shared__ int s[256];
    int t = threadIdx.x;
    int i = blockIdx.x * 256 + t;
    int v = (i < n) ? cnt[i] : 0;
    s[t] = v;
    __syncthreads();
    for (int off = 1; off < 256; off <<= 1) {
        int u = (t >= off) ? s[t - off] : 0;
        __syncthreads();
        s[t] += u;
        __syncthreads();
    }
    if (i < n) excl[i] = s[t] - v;
    if (t == 255) bsums[blockIdx.x] = s[255];
}

__global__ __launch_bounds__(256) void scan_top(int* __restrict__ bsums, int nb)
{
    __shared__ int s[256];
    int t = threadIdx.x;
    int v = (t < nb) ? bsums[t] : 0;
    s[t] = v;
    __syncthreads();
    for (int off = 1; off < 256; off <<= 1) {
        int u = (t >= off) ? s[t - off] : 0;
        __syncthreads();
        s[t] += u;
        __syncthreads();
    }
    if (t < nb) bsums[t] = s[t] - v;
}

__global__ void scan_add(int* __restrict__ excl, const int* __restrict__ bsums,
                         int* __restrict__ cursor, int n)
{
    int i = blockIdx.x * 256 + threadIdx.x;
    if (i < n) {
        int v = excl[i] + bsums[blockIdx.x];
        excl[i] = v;
        cursor[i] = v;
    }
}

__global__ void fill_edges(const int* __restrict__ ei, int* __restrict__ cursor,
                           int* __restrict__ esrc, int E)
{
    int i = blockIdx.x * 256 + threadIdx.x;
    if (i < E) {
        int dst = ei[E + i];
        int pos = atomicAdd(&cursor[dst], 1);
        esrc[pos] = ei[i];
    }
}

// ---------------------------------------------------------------------------
// Fused attention + skip + hm fusion.  One wave per dst node; QKVS layout per
// node: [Q 256 | K 256 | V 256 | S 256] bf16.  hf = alpha*(msg + S) + beta*hm.
// ---------------------------------------------------------------------------
__global__ __launch_bounds__(256) void edge_attn(
    const int* __restrict__ esrc, const int* __restrict__ offs,
    const int* __restrict__ cnts, const ushort* __restrict__ QKVS,
    const ushort* __restrict__ hmb, const float* __restrict__ alpha,
    const float* __restrict__ beta, ushort* __restrict__ hf, int N)
{
    int node = blockIdx.x * 4 + (threadIdx.x >> 6);
    int lane = threadIdx.x & 63;
    if (node >= N) return;
    int start = offs[node];
    int cnt = cnts[node];

    ushort4 qu = *(const ushort4*)(QKVS + (size_t)node * 1024 + lane * 4);
    float qx = bu2f(qu.x), qy = bu2f(qu.y), qz = bu2f(qu.z), qw = bu2f(qu.w);
    const float s = 0.088388347648318447f; // 1/sqrt(128)

    float m = -INFINITY, d = 0.f;
    float a0 = 0.f, a1 = 0.f, a2 = 0.f, a3 = 0.f;

    ushort4 ku_n = {}, vu_n = {};
    if (cnt > 0) {
        int src0 = esrc[start];
        ku_n = *(const ushort4*)(QKVS + (size_t)src0 * 1024 + 256 + lane * 4);
        vu_n = *(const ushort4*)(QKVS + (size_t)src0 * 1024 + 512 + lane * 4);
    }
    for (int i = 0; i < cnt; ++i) {
        ushort4 ku = ku_n, vu = vu_n;
        if (i + 1 < cnt) {
            int srcn = esrc[start + i + 1];
            ku_n = *(const ushort4*)(QKVS + (size_t)srcn * 1024 + 256 + lane * 4);
            vu_n = *(const ushort4*)(QKVS + (size_t)srcn * 1024 + 512 + lane * 4);
        }
        float p = qx * bu2f(ku.x) + qy * bu2f(ku.y)
                + qz * bu2f(ku.z) + qw * bu2f(ku.w);
        p += __shfl_xor(p, 1);
        p += __shfl_xor(p, 2);
        p += __shfl_xor(p, 4);
        p += __shfl_xor(p, 8);
        p += __shfl_xor(p, 16);
        float l = p * s;
        float mn = fmaxf(m, l);
        float sc = __expf(m - mn);
        float pe = __expf(l - mn);
        d = d * sc + pe;
        a0 = a0 * sc + pe * bu2f(vu.x);
        a1 = a1 * sc + pe * bu2f(vu.y);
        a2 = a2 * sc + pe * bu2f(vu.z);
        a3 = a3 * sc + pe * bu2f(vu.w);
        m = mn;
    }
    float invd = (cnt > 0) ? 1.f / fmaxf(d, 1e-16f) : 0.f;
    float o0 = a0 * invd, o1 = a1 * invd, o2 = a2 * invd, o3 = a3 * invd;

    ushort4 su = *(const ushort4*)(QKVS + (size_t)node * 1024 + 768 + lane * 4);
    ushort4 hm = *(const ushort4*)(hmb + (size_t)node * 256 + lane * 4);
    float al = alpha[0], be = beta[0];
    ushort4 o;
    o.x = f2bs(al * (o0 + bu2f(su.x)) + be * bu2f(hm.x));
    o.y = f2bs(al * (o1 + bu2f(su.y)) + be * bu2f(hm.y));
    o.z = f2bs(al * (o2 + bu2f(su.z)) + be * bu2f(hm.z));
    o.w = f2bs(al * (o3 + bu2f(su.w)) + be * bu2f(hm.w));
    *(ushort4*)(hf + (size_t)node * 256 + lane * 4) = o;
}

// ---------------------------------------------------------------------------
// Launch
// ---------------------------------------------------------------------------
extern "C" void kernel_launch(void* const* d_in, const int* in_sizes, int n_in,
                              void* d_out, int out_size, void* d_ws, size_t ws_size,
                              hipStream_t stream)
{
    const float* x_g   = (const float*)d_in[0];
    const int*   ei    = (const int*)d_in[1];
    const float* x_m   = (const float*)d_in[2];
    const float* Wq    = (const float*)d_in[3];
    const float* bq    = (const float*)d_in[4];
    const float* Wk    = (const float*)d_in[5];
    const float* bk    = (const float*)d_in[6];
    const float* Wv    = (const float*)d_in[7];
    const float* bv    = (const float*)d_in[8];
    const float* Wskip = (const float*)d_in[9];
    const float* bskip = (const float*)d_in[10];
    const float* W1    = (const float*)d_in[11];
    const float* b1    = (const float*)d_in[12];
    const float* g1    = (const float*)d_in[13];
    const float* be1   = (const float*)d_in[14];
    const float* W2    = (const float*)d_in[15];
    const float* b2    = (const float*)d_in[16];
    const float* g2    = (const float*)d_in[17];
    const float* be2   = (const float*)d_in[18];
    const float* W3    = (const float*)d_in[19];
    const float* b3    = (const float*)d_in[20];
    const float* alpha = (const float*)d_in[21];
    const float* beta  = (const float*)d_in[22];
    const float* Wc1   = (const float*)d_in[23];
    const float* bc1   = (const float*)d_in[24];
    const float* Wc2   = (const float*)d_in[25];
    const float* bc2   = (const float*)d_in[26];
    float* out = (float*)d_out;

    const int N = in_sizes[0] / 256;
    const int E = in_sizes[1] / 2;

    float* ws = (float*)d_ws;
    // layout (float units)
    ushort* QKVS = (ushort*)ws;                         // N x 1024 bf16
    ushort* bufA = (ushort*)(ws + (size_t)N * 512);     // N x 512 bf16
    ushort* bufB = (ushort*)(ws + (size_t)N * 768);     // N x 512 bf16
    ushort* hmb  = (ushort*)(ws + (size_t)N * 1024);    // N x 256 bf16
    float* wz = ws + (size_t)N * 1152;

    float* sum1 = wz, *sq1 = wz + 512, *sum2 = wz + 1024, *sq2 = wz + 1536;
    int* counts = (int*)(wz + 2048);
    float* wz2 = wz + 2048 + N;
    float* scale1 = wz2, *shift1 = wz2 + 512;
    float* scale2 = wz2 + 1024, *shift2 = wz2 + 1536;
    int* bsums = (int*)(wz2 + 2048);
    int* offs = bsums + 256;
    int* cursor = offs + N;
    int* esrc = cursor + N;
    short* Wall = (short*)(esrc + E);           // 917504 bf16: Q|K|V|S|W1|W2|W3|Wc1
    float* bcat = (float*)(Wall + 917504);      // 1024 f32
    const short* Wcat = Wall;                   // 1024 x 256
    const short* W1b  = Wall + 262144;          // 512 x 256
    const short* W2b  = Wall + 393216;          // 512 x 512
    const short* W3b  = Wall + 655360;          // 256 x 512
    const short* Wc1b = Wall + 786432;          // 512 x 256

    dim3 blk(256);

    // zero: stats (2048 f32) + counts (N i32), contiguous
    hipLaunchKernelGGL(zero_words, dim3(128), blk, 0, stream,
                       (unsigned*)wz, (size_t)(2048 + N));

    // one-shot weight conversion + bias concat
    hipLaunchKernelGGL(pack_params, dim3(898), blk, 0, stream,
                       Wq, Wk, Wv, Wskip, W1, W2, W3, Wc1,
                       bq, bk, bv, bskip, (ushort*)Wall, bcat);

    // CSR build
    const int nb = (N + 255) / 256;
    hipLaunchKernelGGL(count_edges, dim3((E + 255) / 256), blk, 0, stream, ei, counts, E);
    hipLaunchKernelGGL(scan_local, dim3(nb), blk, 0, stream, counts, offs, bsums, N);
    hipLaunchKernelGGL(scan_top, dim3(1), blk, 0, stream, bsums, nb);
    hipLaunchKernelGGL(scan_add, dim3(nb), blk, 0, stream, offs, bsums, cursor, N);
    hipLaunchKernelGGL(fill_edges, dim3((E + 255) / 256), blk, 0, stream, ei, cursor, esrc, E);

    const int g128 = (N + 127) / 128;   // 391
    const int g64 = (N + 63) / 64;      // 782

    // ---- merged dispatch: QKVS (set0, NT=8) + MLP1 (set1, NT=4), both fp32-A ----
    hipLaunchKernelGGL((gemm_v2<0, 128, 256, 0>), dim3(2 * g128), blk, 0, stream,
                       x_g, Wcat, bcat, QKVS, 8,
                       x_m, W1b, b1, bufA, 4,
                       g128, nullptr, nullptr, N, 0);

    // ---- MLP branch ----
    hipLaunchKernelGGL(bn_stats512_b, dim3(512), blk, 0, stream, bufA, sum1, sq1, N);
    hipLaunchKernelGGL(bn_finalize, dim3(2), blk, 0, stream, sum1, sq1, g1, be1, scale1, shift1, N, 512);
    hipLaunchKernelGGL((gemm_v2<1, 64, 512, 1>), dim3(g64), blk, 0, stream,
                       bufA, W2b, b2, bufB, 4,
                       bufA, W2b, b2, bufB, 4,
                       2 * g64, scale1, shift1, N, 0);
    hipLaunchKernelGGL(bn_stats512_b, dim3(512), blk, 0, stream, bufB, sum2, sq2, N);
    hipLaunchKernelGGL(bn_finalize, dim3(2), blk, 0, stream, sum2, sq2, g2, be2, scale2, shift2, N, 512);
    hipLaunchKernelGGL((gemm_v2<1, 64, 512, 1>), dim3(g64), blk, 0, stream,
                       bufB, W3b, b3, hmb, 2,
                       bufB, W3b, b3, hmb, 2,
                       2 * g64, scale2, shift2, N, 0);

    // ---- attention + skip + hm fusion -> hf (bufA) ----
    hipLaunchKernelGGL(edge_attn, dim3((N + 3) / 4), blk, 0, stream,
                       esrc, offs, counts, QKVS, hmb, alpha, beta, bufA, N);

    // ---- classifier head ----
    hipLaunchKernelGGL((gemm_v2<1, 128, 256, 0>), dim3(g128), blk, 0, stream,
                       bufA, Wc1b, bc1, bufB, 4,
                       bufA, Wc1b, bc1, bufB, 4,
                       2 * g128, nullptr, nullptr, N, 1);
    hipLaunchKernelGGL(mfma_gemm_small, dim3(1, (N + 127) / 128), blk, 0, stream,
                       (const short*)bufB, Wc2, bc2, out, N, 512, 40);
}